// Round 2
// baseline (1282.391 us; speedup 1.0000x reference)
//
#include <hip/hip_runtime.h>
#include <cstdint>

#define B__ 16
#define S__ 512
#define NH__ 12
#define HS__ 64
#define H__ 768
#define BH__ 192            // B*NH
#define M__ 8192            // B*S
#define K__ 768
#define N3__ 2304           // 3*H
#define PLANE__ 6291456     // M*K
#define QKV_ELEMS__ 6291456 // BH*S*HS

typedef int      int4v   __attribute__((ext_vector_type(4)));
typedef short    short8  __attribute__((ext_vector_type(8)));
typedef float    float4v __attribute__((ext_vector_type(4)));
typedef unsigned uint2v  __attribute__((ext_vector_type(2)));

__device__ __forceinline__ unsigned short f2bf(float f) {
    unsigned u = __float_as_uint(f);
    u += 0x7fffu + ((u >> 16) & 1u);   // RNE
    return (unsigned short)(u >> 16);
}

// ---------------------------------------------------------------------------
// Kernel 1: per-row scale s_i = mean(|W_i|) in fp64, and sign bytes of W.
// ---------------------------------------------------------------------------
__global__ __launch_bounds__(256)
void prep_w_kernel(const float* __restrict__ Wq, const float* __restrict__ Wk,
                   const float* __restrict__ Wv,
                   double* __restrict__ scales, signed char* __restrict__ sgnW) {
    int wid = threadIdx.x >> 6, lane = threadIdx.x & 63;
    int row = blockIdx.x * 4 + wid;
    if (row >= N3__) return;
    int w = row / 768, i = row - w * 768;
    const float* W = (w == 0) ? Wq : ((w == 1) ? Wk : Wv);
    const float* wr = W + (size_t)i * 768;
    double s = 0.0;
    #pragma unroll
    for (int j = 0; j < 12; j++) {
        float x = wr[lane + j * 64];
        s += fabs((double)x);
        sgnW[(size_t)row * 768 + lane + j * 64] =
            (signed char)((x > 0.f) - (x < 0.f));
    }
    #pragma unroll
    for (int off = 32; off; off >>= 1) s += __shfl_down(s, off);
    if (lane == 0) scales[row] = s * (1.0 / 768.0);
}

// ---------------------------------------------------------------------------
// Kernel 2: x -> fixed point (2^-28 quantum) -> 4 signed i8 digit planes.
// float4 load, one packed dword store per plane (4 elems/thread).
// ---------------------------------------------------------------------------
__global__ __launch_bounds__(256)
void prep_x_kernel(const float* __restrict__ hs, signed char* __restrict__ planes) {
    int idx4 = (blockIdx.x * 256 + threadIdx.x) * 4;
    float4v x4 = *(const float4v*)(hs + idx4);
    unsigned p0 = 0, p1 = 0, p2 = 0, p3 = 0;
    #pragma unroll
    for (int j = 0; j < 4; j++) {
        double d = (double)x4[j] * 268435456.0;           // 2^28
        d = fmin(fmax(d, -2130706400.0), 2130706400.0);
        int v = __double2int_rn(d);
        int e0 = (int)(signed char)(v & 0xff);
        int r1 = (v - e0) >> 8;
        int e1 = (int)(signed char)(r1 & 0xff);
        int r2 = (r1 - e1) >> 8;
        int e2 = (int)(signed char)(r2 & 0xff);
        int r3 = (r2 - e2) >> 8;                          // in [-128,127]
        p0 |= ((unsigned)(unsigned char)e0) << (8 * j);
        p1 |= ((unsigned)(unsigned char)e1) << (8 * j);
        p2 |= ((unsigned)(unsigned char)e2) << (8 * j);
        p3 |= ((unsigned)(unsigned char)(signed char)r3) << (8 * j);
    }
    *(unsigned*)(planes + idx4)               = p0;
    *(unsigned*)(planes + PLANE__ + idx4)     = p1;
    *(unsigned*)(planes + 2 * PLANE__ + idx4) = p2;
    *(unsigned*)(planes + 3 * PLANE__ + idx4) = p3;
}

// ---------------------------------------------------------------------------
// Kernel 3: projection GEMM, exact. OPERAND-SWAPPED MFMA: D = mfma(sgnW, x)
// so reg index r = 4 consecutive OUTPUT COLUMNS per lane -> wide stores:
// qkv 8B (4x bf16), qb/kb packed dword, vbT 4x16B segments.
// ---------------------------------------------------------------------------
__global__ __launch_bounds__(256)
void proj_kernel(const signed char* __restrict__ planes,
                 const signed char* __restrict__ sgnW,
                 const double* __restrict__ scales,
                 const float* __restrict__ bq, const float* __restrict__ bk,
                 const float* __restrict__ bv,
                 unsigned short* __restrict__ qkv,
                 signed char* __restrict__ qb, signed char* __restrict__ kb,
                 signed char* __restrict__ vbT) {
    int wid = threadIdx.x >> 6, lane = threadIdx.x & 63;
    int lrow = lane & 15, kgrp = lane >> 4;
    int wg = blockIdx.x;                       // 4608 = 128 m-slices * 36 n-slices
    int swz = (wg & 7) * 576 + (wg >> 3);      // bijective XCD chunk
    int ms = swz / 36, ns = swz - ms * 36;
    int m0 = ms * 64 + (wid >> 1) * 32;
    int n0 = ns * 64 + (wid & 1) * 32;

    int4v zero = {0, 0, 0, 0};
    int4v acc[2][2][4];
    #pragma unroll
    for (int mt = 0; mt < 2; mt++)
        #pragma unroll
        for (int nt = 0; nt < 2; nt++)
            #pragma unroll
            for (int p = 0; p < 4; p++) acc[mt][nt][p] = zero;

    for (int kc = 0; kc < 12; kc++) {
        int k = kc * 64 + kgrp * 16;
        int4v a[2][4], b[2];
        #pragma unroll
        for (int mt = 0; mt < 2; mt++)
            #pragma unroll
            for (int p = 0; p < 4; p++)
                a[mt][p] = *(const int4v*)(planes + (size_t)p * PLANE__ +
                                           (size_t)(m0 + mt * 16 + lrow) * 768 + k);
        #pragma unroll
        for (int nt = 0; nt < 2; nt++)
            b[nt] = *(const int4v*)(sgnW + (size_t)(n0 + nt * 16 + lrow) * 768 + k);
        #pragma unroll
        for (int mt = 0; mt < 2; mt++)
            #pragma unroll
            for (int nt = 0; nt < 2; nt++)
                #pragma unroll
                for (int p = 0; p < 4; p++)
                    acc[mt][nt][p] = __builtin_amdgcn_mfma_i32_16x16x64_i8(
                        b[nt], a[mt][p], acc[mt][nt][p], 0, 0, 0);
    }

    // block is entirely within one of {q,k,v}: n0 % 64 == 0, 768 % 64 == 0
    int w = (blockIdx.y, n0) / 768;            // n0/768, block-uniform
    const float* bptr = (w == 0) ? bq : ((w == 1) ? bk : bv);

    #pragma unroll
    for (int mt = 0; mt < 2; mt++) {
        int mg = m0 + mt * 16 + lrow;          // lane-indexed output row
        int b_ = mg >> 9, sidx = mg & 511;
        #pragma unroll
        for (int nt = 0; nt < 2; nt++) {
            int ngb = n0 + nt * 16 + kgrp * 4; // 4 consecutive output cols
            int i0 = ngb - w * 768;
            int h = i0 >> 6, d0 = i0 & 63;     // 4 consecutive d, same head
            float4v bias4 = *(const float4v*)(bptr + i0);
            unsigned short bfv[4];
            unsigned sg4 = 0;
            #pragma unroll
            for (int r = 0; r < 4; r++) {
                long long comb = (long long)acc[mt][nt][0][r]
                               + ((long long)acc[mt][nt][1][r] << 8)
                               + ((long long)acc[mt][nt][2][r] << 16)
                               + ((long long)acc[mt][nt][3][r] << 24);
                double T = (double)comb * (1.0 / 268435456.0);
                double qv = fma(scales[ngb + r], T, (double)bias4[r]);
                int sg = (qv > 0.0) - (qv < 0.0);
                bfv[r] = f2bf((float)qv);
                sg4 |= ((unsigned)(unsigned char)(signed char)sg) << (8 * r);
            }
            size_t obase = (((size_t)b_ * NH__ + h) * S__ + sidx) * HS__ + d0;
            uint2v pk = {(unsigned)bfv[0] | ((unsigned)bfv[1] << 16),
                         (unsigned)bfv[2] | ((unsigned)bfv[3] << 16)};
            *(uint2v*)(qkv + (size_t)w * QKV_ELEMS__ + obase) = pk;
            if (w == 0)      *(unsigned*)(qb + obase) = sg4;
            else if (w == 1) *(unsigned*)(kb + obase) = sg4;
            else {
                size_t vb = ((size_t)(b_ * NH__ + h) * HS__ + d0) * S__ + sidx;
                #pragma unroll
                for (int r = 0; r < 4; r++)
                    vbT[vb + (size_t)r * S__] =
                        (signed char)((sg4 >> (8 * r)) & 0xff);
            }
        }
    }
}

// ---------------------------------------------------------------------------
// Kernel 4: X @ X^T * 0.125, fused over q/k/v. OPERAND-SWAPPED MFMA so each
// lane stores float4 (4 consecutive cols of one output row).
// ---------------------------------------------------------------------------
__global__ __launch_bounds__(256)
void score3_kernel(const unsigned short* __restrict__ qkv,
                   float* __restrict__ qsc, float* __restrict__ ksc,
                   float* __restrict__ vsc) {
    int wid = threadIdx.x >> 6, lane = threadIdx.x & 63;
    int lrow = lane & 15, kgrp = lane >> 4;
    int wg = blockIdx.x;                         // 36864 = 3 * 192 * 64
    int swz = (wg & 7) * 4608 + (wg >> 3);       // bijective XCD chunk
    int z = swz / 12288;
    int rem = swz - z * 12288;
    int bh = rem >> 6;
    int tile = rem & 63;
    int mb = tile >> 3, nb = tile & 7;
    int m0 = mb * 64 + (wid >> 1) * 32;
    int n0 = nb * 64 + (wid & 1) * 32;
    const unsigned short* Xb =
        qkv + (size_t)z * QKV_ELEMS__ + (size_t)bh * S__ * HS__;

    float4v acc[2][2];
    #pragma unroll
    for (int mt = 0; mt < 2; mt++)
        #pragma unroll
        for (int nt = 0; nt < 2; nt++) acc[mt][nt] = (float4v){0.f, 0.f, 0.f, 0.f};

    #pragma unroll
    for (int kc = 0; kc < 2; kc++) {
        int k = kc * 32 + kgrp * 8;
        short8 a[2], b[2];
        #pragma unroll
        for (int mt = 0; mt < 2; mt++)
            a[mt] = *(const short8*)(Xb + (size_t)(m0 + mt * 16 + lrow) * HS__ + k);
        #pragma unroll
        for (int nt = 0; nt < 2; nt++)
            b[nt] = *(const short8*)(Xb + (size_t)(n0 + nt * 16 + lrow) * HS__ + k);
        #pragma unroll
        for (int mt = 0; mt < 2; mt++)
            #pragma unroll
            for (int nt = 0; nt < 2; nt++)
                acc[mt][nt] = __builtin_amdgcn_mfma_f32_16x16x32_bf16(
                    b[nt], a[mt], acc[mt][nt], 0, 0, 0);
    }

    float* ob = (z == 0 ? qsc : (z == 1 ? ksc : vsc)) + (size_t)bh * S__ * S__;
    #pragma unroll
    for (int mt = 0; mt < 2; mt++) {
        int row = m0 + mt * 16 + lrow;
        #pragma unroll
        for (int nt = 0; nt < 2; nt++) {
            int c0 = n0 + nt * 16 + kgrp * 4;
            float4v o4 = {acc[mt][nt][0] * 0.125f, acc[mt][nt][1] * 0.125f,
                          acc[mt][nt][2] * 0.125f, acc[mt][nt][3] * 0.125f};
            *(float4v*)(ob + (size_t)row * S__ + c0) = o4;
        }
    }
}

// ---------------------------------------------------------------------------
// Kernel 5: attention scores (exact, i8 MFMA, operand-swapped -> float4
// stores + packed probs2 dword LDS writes), then context = 0.5 * probs2 @ vb
// (operand-swapped -> float4 ctx stores).
// ---------------------------------------------------------------------------
__global__ __launch_bounds__(256)
void attn_kernel(const signed char* __restrict__ qb,
                 const signed char* __restrict__ kb,
                 const signed char* __restrict__ vbT,
                 const float* __restrict__ mask,
                 float* __restrict__ attn_out, float* __restrict__ ctx_out) {
    __shared__ signed char probs2[4][16][528];   // 528 = 512+16 pad
    int wid = threadIdx.x >> 6, lane = threadIdx.x & 63;
    int lrow = lane & 15, kgrp = lane >> 4;
    int wg = blockIdx.x;                         // 1536 = 192 * 8
    int swz = (wg & 7) * 192 + (wg >> 3);        // bijective XCD chunk
    int bh = swz >> 3;
    int mb = swz & 7;
    int b_ = bh / NH__, h = bh - b_ * NH__;
    int m0 = mb * 64 + wid * 16;

    const signed char* qbb = qb + (size_t)bh * S__ * HS__;
    const signed char* kbb = kb + (size_t)bh * S__ * HS__;
    const float* mrow = mask + (size_t)b_ * S__;
    float* ao = attn_out + (size_t)bh * S__ * S__;

    int4v zero = {0, 0, 0, 0};
    int4v qfrag = *(const int4v*)(qbb + (size_t)(m0 + lrow) * HS__ + kgrp * 16);

    for (int nt = 0; nt < 32; nt++) {
        int4v kfrag = *(const int4v*)(kbb + (size_t)(nt * 16 + lrow) * HS__ + kgrp * 16);
        // swapped: D[i][j], i = k-col (kgrp*4+r), j = q-row (lrow)
        int4v dacc = __builtin_amdgcn_mfma_i32_16x16x64_i8(kfrag, qfrag, zero, 0, 0, 0);
        int c0 = nt * 16 + kgrp * 4;             // 4 consecutive k-cols
        float4v m4 = *(const float4v*)(mrow + c0);
        float4v sc4;
        unsigned pk = 0;
        #pragma unroll
        for (int r = 0; r < 4; r++) {
            float sc = (float)dacc[r] * 0.125f + m4[r];
            sc4[r] = sc;
            pk |= ((unsigned)(unsigned char)(sc > 0.f ? 2 : (sc < 0.f ? 0 : 1)))
                  << (8 * r);
        }
        *(float4v*)(ao + (size_t)(m0 + lrow) * S__ + c0) = sc4;
        *(unsigned*)(&probs2[wid][lrow][c0]) = pk;
    }

    const signed char* vt = vbT + (size_t)bh * HS__ * S__;
    int4v acc2[4];
    #pragma unroll
    for (int dt = 0; dt < 4; dt++) acc2[dt] = zero;

    for (int kc = 0; kc < 8; kc++) {
        int k = kc * 64 + kgrp * 16;
        int4v a2 = *(const int4v*)(&probs2[wid][lrow][k]);
        #pragma unroll
        for (int dt = 0; dt < 4; dt++) {
            int4v b2 = *(const int4v*)(vt + (size_t)(dt * 16 + lrow) * S__ + k);
            // swapped: D[i][j], i = d (kgrp*4+r), j = q-row (lrow)
            acc2[dt] = __builtin_amdgcn_mfma_i32_16x16x64_i8(b2, a2, acc2[dt], 0, 0, 0);
        }
    }

    int srow = m0 + lrow;
    #pragma unroll
    for (int dt = 0; dt < 4; dt++) {
        int d0 = dt * 16 + kgrp * 4;
        float4v c4 = {(float)acc2[dt][0] * 0.5f, (float)acc2[dt][1] * 0.5f,
                      (float)acc2[dt][2] * 0.5f, (float)acc2[dt][3] * 0.5f};
        *(float4v*)(ctx_out + ((size_t)b_ * S__ + srow) * H__ + h * HS__ + d0) = c4;
    }
}

// ---------------------------------------------------------------------------
extern "C" void kernel_launch(void* const* d_in, const int* in_sizes, int n_in,
                              void* d_out, int out_size, void* d_ws, size_t ws_size,
                              hipStream_t stream) {
    const float* hs   = (const float*)d_in[0];
    const float* mask = (const float*)d_in[1];
    const float* Wq   = (const float*)d_in[2];
    const float* bq   = (const float*)d_in[3];
    const float* Wk   = (const float*)d_in[4];
    const float* bk   = (const float*)d_in[5];
    const float* Wv   = (const float*)d_in[6];
    const float* bv   = (const float*)d_in[7];

    char* ws = (char*)d_ws;
    double*         scales = (double*)(ws);                    // 18432 B
    signed char*    sgnW   = (signed char*)(ws + 18432);       // 1769472 B
    signed char*    planes = (signed char*)(ws + 1787904);     // 25165824 B
    unsigned short* qkv    = (unsigned short*)(ws + 26953728); // 37748736 B
    signed char*    qb     = (signed char*)(ws + 64702464);    // 6291456 B
    signed char*    kb     = (signed char*)(ws + 70993920);    // 6291456 B
    signed char*    vbT    = (signed char*)(ws + 77285376);    // 6291456 B

    float* out  = (float*)d_out;
    float* ctx  = out;                    // [16,512,768]
    float* attn = out + 6291456;          // [16,12,512,512]
    float* vsc  = out + 56623104;         // value_scores
    float* qsc  = out + 106954752;        // query_scores
    float* ksc  = out + 157286400;        // key_scores

    hipLaunchKernelGGL(prep_w_kernel, dim3(576), dim3(256), 0, stream,
                       Wq, Wk, Wv, scales, sgnW);
    hipLaunchKernelGGL(prep_x_kernel, dim3(PLANE__ / 1024), dim3(256), 0, stream,
                       hs, planes);
    hipLaunchKernelGGL(proj_kernel, dim3(4608), dim3(256), 0, stream,
                       planes, sgnW, scales, bq, bk, bv, qkv, qb, kb, vbT);
    hipLaunchKernelGGL(score3_kernel, dim3(36864), dim3(256), 0, stream,
                       qkv, qsc, ksc, vsc);
    hipLaunchKernelGGL(attn_kernel, dim3(1536), dim3(256), 0, stream,
                       qb, kb, vbT, mask, attn, ctx);
}